// Round 11
// baseline (631.349 us; speedup 1.0000x reference)
//
#include <hip/hip_runtime.h>
#include <cstdint>

typedef _Float16 half8 __attribute__((ext_vector_type(8)));
typedef _Float16 half4 __attribute__((ext_vector_type(4)));
typedef float f32x4 __attribute__((ext_vector_type(4)));

#define T_STEPS 16
#define NB 8
#define CCH 64
#define HH 64
#define WW 64
#define HW 4096
#define NCHW (NB * CCH * HW)          // 2097152
#define XTSTR (NB * 2 * CCH * HW)

#define CI_PAD 40                      // halves per (r,c) cell: 80B stride, 16B aligned
#define IN_LDS (4 * 66 * CI_PAD)       // 21120 B per plane

__device__ __forceinline__ void split2h(float x, _Float16& hi, _Float16& lo) {
    hi = (_Float16)x;
    lo = (_Float16)((x - (float)hi) * 2048.0f);
}

// ---------------------------------------------------------------------------
// One-time weight prepack into split planes:
// layout [g][tap 9][chunk 2][ch 2][co 32][ci 32] halves (ci fastest)
// ---------------------------------------------------------------------------
__global__ __launch_bounds__(256) void prep_w(const float* __restrict__ w_rz,
                                              const float* __restrict__ w_f,
                                              _Float16* __restrict__ w_hi,
                                              _Float16* __restrict__ w_lo) {
    int i = blockIdx.x * 256 + threadIdx.x;
    if (i >= 2 * 9 * 2 * 2 * 32 * 32) return;
    int ci = i & 31, co = (i >> 5) & 31, ch = (i >> 10) & 1, chunk = (i >> 11) & 1;
    int gt = i >> 12; int tap = gt % 9; int g = gt / 9;
    const float* w = g ? w_f : w_rz;
    float v = w[(size_t)((ch * 32 + co) * CCH + (chunk * 32 + ci)) * 9 + tap];
    _Float16 hi, lo; split2h(v, hi, lo);
    w_hi[i] = hi; w_lo[i] = lo;
}

// ---------------------------------------------------------------------------
// Input staging (chunk of 32 ci, both planes). Direct form and T14 split form.
// ---------------------------------------------------------------------------
__device__ __forceinline__ void stage_pl(const _Float16* __restrict__ ph,
                                         const _Float16* __restrict__ pl,
                                         int n, int y0, int chunk,
                                         _Float16* __restrict__ s_hi,
                                         _Float16* __restrict__ s_lo, int tid) {
    #pragma unroll
    for (int it = 0; it < 5; ++it) {
        int i = tid + it * 256;
        if (i >= 1056) break;                 // 4 rows x 66 cols x 4 granules
        int gg = i & 3; int tmp = i >> 2; int c = tmp % 66; int r = tmp / 66;
        int gr = y0 - 1 + r, gc = c - 1;
        uint4 uh = make_uint4(0, 0, 0, 0), ul = make_uint4(0, 0, 0, 0);
        if ((unsigned)gr < 64u && (unsigned)gc < 64u) {
            size_t base = (((size_t)n * 64 + gr) * 64 + gc) * 64 + chunk * 32 + gg * 8;
            uh = *(const uint4*)(ph + base);
            ul = *(const uint4*)(pl + base);
        }
        int off = (r * 66 + c) * CI_PAD + gg * 8;
        *(uint4*)&s_hi[off] = uh;
        *(uint4*)&s_lo[off] = ul;
    }
}

__device__ __forceinline__ void stage_issue2(const _Float16* __restrict__ ph,
                                             const _Float16* __restrict__ pl,
                                             int n, int y0, int chunk, int tid,
                                             uint4* vh, uint4* vl) {
    #pragma unroll
    for (int it = 0; it < 5; ++it) {
        int i = tid + it * 256;
        vh[it] = make_uint4(0, 0, 0, 0);
        vl[it] = make_uint4(0, 0, 0, 0);
        if (i < 1056) {
            int gg = i & 3; int tmp = i >> 2; int c = tmp % 66; int r = tmp / 66;
            int gr = y0 - 1 + r, gc = c - 1;
            if ((unsigned)gr < 64u && (unsigned)gc < 64u) {
                size_t base = (((size_t)n * 64 + gr) * 64 + gc) * 64 + chunk * 32 + gg * 8;
                vh[it] = *(const uint4*)(ph + base);
                vl[it] = *(const uint4*)(pl + base);
            }
        }
    }
}
__device__ __forceinline__ void stage_write2(const uint4* vh, const uint4* vl,
                                             _Float16* __restrict__ s_hi,
                                             _Float16* __restrict__ s_lo, int tid) {
    #pragma unroll
    for (int it = 0; it < 5; ++it) {
        int i = tid + it * 256;
        if (i < 1056) {
            int gg = i & 3, cell = i >> 2;
            int off = cell * CI_PAD + gg * 8;
            *(uint4*)&s_hi[off] = vh[it];
            *(uint4*)&s_lo[off] = vl[it];
        }
    }
}

// ---------------------------------------------------------------------------
// Weights: all 9 taps of one ci-chunk (one co-half). 18 uint2 per thread.
// ---------------------------------------------------------------------------
__device__ __forceinline__ void wload9(const _Float16* __restrict__ wh,
                                       const _Float16* __restrict__ wl,
                                       int chunk, int ch, int tid,
                                       uint2* uh, uint2* ul) {
    #pragma unroll
    for (int tap = 0; tap < 9; ++tap) {
        size_t base = (size_t)((tap * 2 + chunk) * 2 + ch) * 1024 + tid * 4;
        uh[tap] = *(const uint2*)(wh + base);
        ul[tap] = *(const uint2*)(wl + base);
    }
}
__device__ __forceinline__ void wwrite9(const uint2* uh, const uint2* ul,
                                        _Float16 (*sw)[2][1024], int tid) {
    int co = tid >> 3, j = tid & 7;
    int pos = ((j >> 1) ^ (co ^ (co >> 2))) & 3;       // granule swizzle (verified r3)
    int off = co * 32 + pos * 8 + (j & 1) * 4;
    #pragma unroll
    for (int tap = 0; tap < 9; ++tap) {
        *(uint2*)&sw[tap][0][off] = uh[tap];
        *(uint2*)&sw[tap][1][off] = ul[tap];
    }
}

// ---------------------------------------------------------------------------
// One chunk's 9-tap MFMA run (108 MFMAs), barrier-free.
// ---------------------------------------------------------------------------
__device__ __forceinline__ void chunk_mfma(const _Float16* __restrict__ s_in_h,
    const _Float16* __restrict__ s_in_l, _Float16 (*s_w)[2][1024],
    int wv, int lg, int ln, int aoff, f32x4 acc1[2][2], f32x4 acc2[2][2]) {
    #pragma unroll
    for (int tap = 0; tap < 9; ++tap) {
        const int ty = tap / 3, tx = tap - ty * 3;
        half8 afh[2], afl[2];
        #pragma unroll
        for (int ct = 0; ct < 2; ++ct) {
            afh[ct] = *(const half8*)&s_w[tap][0][ct * 512 + aoff];
            afl[ct] = *(const half8*)&s_w[tap][1][ct * 512 + aoff];
        }
        half8 bfh[2], bfl[2];
        #pragma unroll
        for (int st = 0; st < 2; ++st) {
            int sp = wv * 32 + st * 16 + ln;
            int boff = (((sp >> 6) + ty) * 66 + (sp & 63) + tx) * CI_PAD + lg * 8;
            bfh[st] = *(const half8*)&s_in_h[boff];
            bfl[st] = *(const half8*)&s_in_l[boff];
        }
        #pragma unroll
        for (int ct = 0; ct < 2; ++ct)
            #pragma unroll
            for (int st = 0; st < 2; ++st) {
                acc1[ct][st] = __builtin_amdgcn_mfma_f32_16x16x32_f16(afh[ct], bfh[st], acc1[ct][st], 0, 0, 0);
                acc2[ct][st] = __builtin_amdgcn_mfma_f32_16x16x32_f16(afh[ct], bfl[st], acc2[ct][st], 0, 0, 0);
                acc2[ct][st] = __builtin_amdgcn_mfma_f32_16x16x32_f16(afl[ct], bfh[st], acc2[ct][st], 0, 0, 0);
            }
    }
}

// ---------------------------------------------------------------------------
// Conv core v4: 3 barriers; chunk-resident weights; epilogue-operand prefetch
// issued AFTER B0 (hides under chunk-0 MFMAs, kept out of B0's drain);
// T5 setprio around the MFMA clusters.
// ---------------------------------------------------------------------------
template<class PF>
__device__ __forceinline__ void conv_core(const _Float16* __restrict__ in_h,
    const _Float16* __restrict__ in_l, const _Float16* __restrict__ wh,
    const _Float16* __restrict__ wl, int n, int y0, int ch, int tid,
    f32x4 acc1[2][2], f32x4 acc2[2][2],
    _Float16* s_in_h, _Float16* s_in_l, _Float16 (*s_w)[2][1024], PF&& prefetch) {

    int wv = tid >> 6, l = tid & 63, lg = l >> 4, ln = l & 15;
    int aoff = ln * 32 + ((lg ^ ln ^ (ln >> 2)) & 3) * 8;

    // initial stage: input chunk0 + weights chunk0 (only loads B0 must drain)
    stage_pl(in_h, in_l, n, y0, 0, s_in_h, s_in_l, tid);
    {
        uint2 w0h[9], w0l[9];
        wload9(wh, wl, 0, ch, tid, w0h, w0l);
        wwrite9(w0h, w0l, s_w, tid);
    }
    __syncthreads();                                   // B0

    // chunk-1 staging loads, then epilogue-operand prefetch: all complete
    // under chunk-0's ~108-MFMA run, drained (already done) at B1.
    uint4 sh1[5], sl1[5];
    uint2 w1h[9], w1l[9];
    stage_issue2(in_h, in_l, n, y0, 1, tid, sh1, sl1);
    wload9(wh, wl, 1, ch, tid, w1h, w1l);
    prefetch();

    __builtin_amdgcn_s_setprio(1);
    chunk_mfma(s_in_h, s_in_l, s_w, wv, lg, ln, aoff, acc1, acc2);
    __builtin_amdgcn_s_setprio(0);

    __syncthreads();                                   // B1: reads of c0 done
    stage_write2(sh1, sl1, s_in_h, s_in_l, tid);
    wwrite9(w1h, w1l, s_w, tid);
    __syncthreads();                                   // B2: c1 visible

    __builtin_amdgcn_s_setprio(1);
    chunk_mfma(s_in_h, s_in_l, s_w, wv, lg, ln, aoff, acc1, acc2);
    __builtin_amdgcn_s_setprio(0);
}

// ---------------------------------------------------------------------------
// Kernel A: f = sigmoid(conv(prev_y, w_rz) + b_rz + xi_i); a = prev_y * f.
// ---------------------------------------------------------------------------
template<bool ZERO>
__global__ __launch_bounds__(256, 2) void kA(
    const _Float16* __restrict__ y_hi, const _Float16* __restrict__ y_lo,
    const _Float16* __restrict__ wh, const _Float16* __restrict__ wl,
    const float* __restrict__ b_rz, const float* __restrict__ xt_t,
    float* __restrict__ f_out,
    _Float16* __restrict__ a_hi, _Float16* __restrict__ a_lo) {

    __shared__ __align__(16) _Float16 s_in_h[IN_LDS];
    __shared__ __align__(16) _Float16 s_in_l[IN_LDS];
    __shared__ __align__(16) _Float16 s_w[9][2][1024];

    int tid = threadIdx.x, wv = tid >> 6, l = tid & 63, lg = l >> 4, ln = l & 15;
    int bid = ((blockIdx.x & 7) << 6) | (blockIdx.x >> 3);   // XCD swizzle
    int n = bid >> 6, strip = (bid >> 1) & 31, ch = bid & 1, y0 = strip * 2;

    float xi_r[2][2][4];
    half4 pyh_r[2][2], pyl_r[2][2];
    float brz_[2][4];
    auto prefetch = [&]() {
        #pragma unroll
        for (int ct = 0; ct < 2; ++ct) {
            #pragma unroll
            for (int st = 0; st < 2; ++st) {
                int sp = wv * 32 + st * 16 + ln, row = y0 + (sp >> 6), col = sp & 63;
                size_t pb = (((size_t)n * 64 + row) * 64 + col) * 64
                          + ch * 32 + ct * 16 + lg * 4;
                if (!ZERO) {
                    pyh_r[ct][st] = *(const half4*)(y_hi + pb);
                    pyl_r[ct][st] = *(const half4*)(y_lo + pb);
                } else {
                    pyh_r[ct][st] = half4{}; pyl_r[ct][st] = half4{};
                }
                #pragma unroll
                for (int r = 0; r < 4; ++r) {
                    int co = ch * 32 + ct * 16 + lg * 4 + r;
                    xi_r[ct][st][r] = xt_t[((n * 2 * CCH + co) * HH + row) * WW + col];
                }
            }
            #pragma unroll
            for (int r = 0; r < 4; ++r)
                brz_[ct][r] = b_rz[ch * 32 + ct * 16 + lg * 4 + r];
        }
    };

    f32x4 acc1[2][2] = {}, acc2[2][2] = {};
    if (!ZERO)
        conv_core(y_hi, y_lo, wh, wl, n, y0, ch, tid, acc1, acc2,
                  s_in_h, s_in_l, s_w, prefetch);
    else
        prefetch();

    #pragma unroll
    for (int ct = 0; ct < 2; ++ct)
        #pragma unroll
        for (int st = 0; st < 2; ++st) {
            int sp = wv * 32 + st * 16 + ln, row = y0 + (sp >> 6), col = sp & 63;
            size_t pb = (((size_t)n * 64 + row) * 64 + col) * 64 + ch * 32 + ct * 16 + lg * 4;
            half4 avh, avl;
            #pragma unroll
            for (int r = 0; r < 4; ++r) {
                int co = ch * 32 + ct * 16 + lg * 4 + r;
                float conv = ZERO ? 0.0f
                    : (acc1[ct][st][r] + acc2[ct][st][r] * (1.0f / 2048.0f));
                int idx = ((n * CCH + co) * HH + row) * WW + col;
                float s = conv + brz_[ct][r] + xi_r[ct][st][r];
                float f = 1.0f / (1.0f + expf(-s));
                f_out[idx] = f;
                float py = (float)pyh_r[ct][st][r] + (float)pyl_r[ct][st][r] * (1.0f / 2048.0f);
                float a = py * f;
                _Float16 hi, lo; split2h(a, hi, lo);
                avh[r] = hi; avl[r] = lo;
            }
            if (!ZERO) {
                *(half4*)(a_hi + pb) = avh;
                *(half4*)(a_lo + pb) = avl;
            }
        }
}

// ---------------------------------------------------------------------------
// Kernel B: g = tanh(conv(a, w_f) + b_f + xi_f); GRU/spike update; outputs +
// split y planes.
// ---------------------------------------------------------------------------
template<bool ZERO>
__global__ __launch_bounds__(256, 2) void kB(
    const _Float16* __restrict__ a_hi, const _Float16* __restrict__ a_lo,
    const _Float16* __restrict__ wh, const _Float16* __restrict__ wl,
    const float* __restrict__ b_f, const float* __restrict__ xt_t,
    const float* __restrict__ f_in, const float* __restrict__ thr_rp,
    float* __restrict__ h_buf, float* __restrict__ ys,
    float* __restrict__ ev, float* __restrict__ nd,
    _Float16* __restrict__ y_hi, _Float16* __restrict__ y_lo) {

    __shared__ __align__(16) _Float16 s_in_h[IN_LDS];
    __shared__ __align__(16) _Float16 s_in_l[IN_LDS];
    __shared__ __align__(16) _Float16 s_w[9][2][1024];

    int tid = threadIdx.x, wv = tid >> 6, l = tid & 63, lg = l >> 4, ln = l & 15;
    int bid = ((blockIdx.x & 7) << 6) | (blockIdx.x >> 3);
    int n = bid >> 6, strip = (bid >> 1) & 31, ch = bid & 1, y0 = strip * 2;

    float xi_r[2][2][4], f_r[2][2][4], h_r[2][2][4];
    float thr_r[2], bf_[2][4];
    auto prefetch = [&]() {
        #pragma unroll
        for (int st = 0; st < 2; ++st) {
            int sp = wv * 32 + st * 16 + ln, row = y0 + (sp >> 6), col = sp & 63;
            thr_r[st] = thr_rp[row * WW + col];
        }
        #pragma unroll
        for (int ct = 0; ct < 2; ++ct) {
            #pragma unroll
            for (int st = 0; st < 2; ++st) {
                int sp = wv * 32 + st * 16 + ln, row = y0 + (sp >> 6), col = sp & 63;
                #pragma unroll
                for (int r = 0; r < 4; ++r) {
                    int co = ch * 32 + ct * 16 + lg * 4 + r;
                    int idx = ((n * CCH + co) * HH + row) * WW + col;
                    xi_r[ct][st][r] = xt_t[((n * 2 * CCH + CCH + co) * HH + row) * WW + col];
                    f_r[ct][st][r]  = f_in[idx];
                    h_r[ct][st][r]  = ZERO ? 0.0f : h_buf[idx];
                }
            }
            #pragma unroll
            for (int r = 0; r < 4; ++r)
                bf_[ct][r] = b_f[ch * 32 + ct * 16 + lg * 4 + r];
        }
    };

    f32x4 acc1[2][2] = {}, acc2[2][2] = {};
    if (!ZERO)
        conv_core(a_hi, a_lo, wh, wl, n, y0, ch, tid, acc1, acc2,
                  s_in_h, s_in_l, s_w, prefetch);
    else
        prefetch();

    #pragma unroll
    for (int ct = 0; ct < 2; ++ct)
        #pragma unroll
        for (int st = 0; st < 2; ++st) {
            int sp = wv * 32 + st * 16 + ln, row = y0 + (sp >> 6), col = sp & 63;
            float thr = 1.0f / (1.0f + expf(-thr_r[st]));
            size_t pb = (((size_t)n * 64 + row) * 64 + col) * 64 + ch * 32 + ct * 16 + lg * 4;
            half4 yvh, yvl;
            #pragma unroll
            for (int r = 0; r < 4; ++r) {
                int co = ch * 32 + ct * 16 + lg * 4 + r;
                float conv = ZERO ? 0.0f
                    : (acc1[ct][st][r] + acc2[ct][st][r] * (1.0f / 2048.0f));
                int idx = ((n * CCH + co) * HH + row) * WW + col;
                float s  = conv + bf_[ct][r] + xi_r[ct][st][r];
                float e2 = expf(2.0f * s);
                float g  = 1.0f - 2.0f / (e2 + 1.0f);       // tanh(s)
                float f  = f_r[ct][st][r];
                float hp = h_r[ct][st][r];
                float h  = (1.0f - f) * hp + f * g;
                float d  = h - thr;
                bool  e  = d > 0.0f;
                float y  = e ? h : 0.0f;
                ys[idx] = y;
                ev[idx] = e ? 1.0f : 0.0f;
                nd[idx] = (d < 0.0f) ? (thr - h) : 0.0f;
                h_buf[idx] = e ? d : h;                     // h - event*thr
                _Float16 hi, lo; split2h(y, hi, lo);
                yvh[r] = hi; yvl[r] = lo;
            }
            *(half4*)(y_hi + pb) = yvh;
            *(half4*)(y_lo + pb) = yvl;
        }
}

// ---------------------------------------------------------------------------
extern "C" void kernel_launch(void* const* d_in, const int* in_sizes, int n_in,
                              void* d_out, int out_size, void* d_ws, size_t ws_size,
                              hipStream_t stream) {
    (void)in_sizes; (void)n_in; (void)out_size; (void)ws_size;

    const float* xt     = (const float*)d_in[0];
    const float* w_rz   = (const float*)d_in[1];
    const float* b_rz   = (const float*)d_in[2];
    const float* w_f    = (const float*)d_in[3];
    const float* b_f    = (const float*)d_in[4];
    const float* thr_rp = (const float*)d_in[5];

    float* out = (float*)d_out;
    _Float16* y_hi = (_Float16*)d_ws;                 // 4 MB each plane
    _Float16* y_lo = y_hi + NCHW;
    _Float16* a_hi = y_lo + NCHW;
    _Float16* a_lo = a_hi + NCHW;
    float*    f_buf = (float*)(a_lo + NCHW);          // 8 MB
    float*    h_buf = f_buf + NCHW;                   // 8 MB
    _Float16* w_hi  = (_Float16*)(h_buf + NCHW);      // 73728 halves
    _Float16* w_lo  = w_hi + 73728;                   // total ~32.3 MB

    float* ys0 = out;
    float* ev0 = out + (size_t)T_STEPS * NCHW;
    float* nd0 = ev0 + (size_t)T_STEPS * NCHW;

    prep_w<<<288, 256, 0, stream>>>(w_rz, w_f, w_hi, w_lo);
    const _Float16* whA = w_hi,         * wlA = w_lo;
    const _Float16* whB = w_hi + 36864, * wlB = w_lo + 36864;

    dim3 grid(512), block(256);
    for (int t = 0; t < T_STEPS; ++t) {
        const float* xt_t = xt + (size_t)t * XTSTR;
        float* ys_t = ys0 + (size_t)t * NCHW;
        float* ev_t = ev0 + (size_t)t * NCHW;
        float* nd_t = nd0 + (size_t)t * NCHW;
        if (t == 0) {
            kA<true><<<grid, block, 0, stream>>>(y_hi, y_lo, whA, wlA, b_rz, xt_t,
                                                 f_buf, a_hi, a_lo);
            kB<true><<<grid, block, 0, stream>>>(a_hi, a_lo, whB, wlB, b_f, xt_t,
                                                 f_buf, thr_rp, h_buf,
                                                 ys_t, ev_t, nd_t, y_hi, y_lo);
        } else {
            kA<false><<<grid, block, 0, stream>>>(y_hi, y_lo, whA, wlA, b_rz, xt_t,
                                                  f_buf, a_hi, a_lo);
            kB<false><<<grid, block, 0, stream>>>(a_hi, a_lo, whB, wlB, b_f, xt_t,
                                                  f_buf, thr_rp, h_buf,
                                                  ys_t, ev_t, nd_t, y_hi, y_lo);
        }
    }
}

// Round 12
// 583.406 us; speedup vs baseline: 1.0822x; 1.0822x over previous
//
#include <hip/hip_runtime.h>
#include <cstdint>

typedef _Float16 half8 __attribute__((ext_vector_type(8)));
typedef _Float16 half4 __attribute__((ext_vector_type(4)));
typedef float f32x4 __attribute__((ext_vector_type(4)));

#define T_STEPS 16
#define NB 8
#define CCH 64
#define HH 64
#define WW 64
#define HW 4096
#define NCHW (NB * CCH * HW)          // 2097152
#define XTSTR (NB * 2 * CCH * HW)

#define CI_PAD 40                      // halves per (r,c) cell: 80B stride, 16B aligned
#define IN_LDS (4 * 66 * CI_PAD)       // 21120 B per plane

__device__ __forceinline__ void split2h(float x, _Float16& hi, _Float16& lo) {
    hi = (_Float16)x;
    lo = (_Float16)((x - (float)hi) * 2048.0f);
}

// ---------------------------------------------------------------------------
// One-time weight prepack into split planes:
// layout [g][tap 9][chunk 2][ch 2][co 32][ci 32] halves (ci fastest)
// ---------------------------------------------------------------------------
__global__ __launch_bounds__(256) void prep_w(const float* __restrict__ w_rz,
                                              const float* __restrict__ w_f,
                                              _Float16* __restrict__ w_hi,
                                              _Float16* __restrict__ w_lo) {
    int i = blockIdx.x * 256 + threadIdx.x;
    if (i >= 2 * 9 * 2 * 2 * 32 * 32) return;
    int ci = i & 31, co = (i >> 5) & 31, ch = (i >> 10) & 1, chunk = (i >> 11) & 1;
    int gt = i >> 12; int tap = gt % 9; int g = gt / 9;
    const float* w = g ? w_f : w_rz;
    float v = w[(size_t)((ch * 32 + co) * CCH + (chunk * 32 + ci)) * 9 + tap];
    _Float16 hi, lo; split2h(v, hi, lo);
    w_hi[i] = hi; w_lo[i] = lo;
}

// ---------------------------------------------------------------------------
// Input staging (chunk of 32 ci, both planes). Direct form and T14 split form.
// ---------------------------------------------------------------------------
__device__ __forceinline__ void stage_pl(const _Float16* __restrict__ ph,
                                         const _Float16* __restrict__ pl,
                                         int n, int y0, int chunk,
                                         _Float16* __restrict__ s_hi,
                                         _Float16* __restrict__ s_lo, int tid) {
    #pragma unroll
    for (int it = 0; it < 5; ++it) {
        int i = tid + it * 256;
        if (i >= 1056) break;                 // 4 rows x 66 cols x 4 granules
        int gg = i & 3; int tmp = i >> 2; int c = tmp % 66; int r = tmp / 66;
        int gr = y0 - 1 + r, gc = c - 1;
        uint4 uh = make_uint4(0, 0, 0, 0), ul = make_uint4(0, 0, 0, 0);
        if ((unsigned)gr < 64u && (unsigned)gc < 64u) {
            size_t base = (((size_t)n * 64 + gr) * 64 + gc) * 64 + chunk * 32 + gg * 8;
            uh = *(const uint4*)(ph + base);
            ul = *(const uint4*)(pl + base);
        }
        int off = (r * 66 + c) * CI_PAD + gg * 8;
        *(uint4*)&s_hi[off] = uh;
        *(uint4*)&s_lo[off] = ul;
    }
}

__device__ __forceinline__ void stage_issue2(const _Float16* __restrict__ ph,
                                             const _Float16* __restrict__ pl,
                                             int n, int y0, int chunk, int tid,
                                             uint4* vh, uint4* vl) {
    #pragma unroll
    for (int it = 0; it < 5; ++it) {
        int i = tid + it * 256;
        vh[it] = make_uint4(0, 0, 0, 0);
        vl[it] = make_uint4(0, 0, 0, 0);
        if (i < 1056) {
            int gg = i & 3; int tmp = i >> 2; int c = tmp % 66; int r = tmp / 66;
            int gr = y0 - 1 + r, gc = c - 1;
            if ((unsigned)gr < 64u && (unsigned)gc < 64u) {
                size_t base = (((size_t)n * 64 + gr) * 64 + gc) * 64 + chunk * 32 + gg * 8;
                vh[it] = *(const uint4*)(ph + base);
                vl[it] = *(const uint4*)(pl + base);
            }
        }
    }
}
__device__ __forceinline__ void stage_write2(const uint4* vh, const uint4* vl,
                                             _Float16* __restrict__ s_hi,
                                             _Float16* __restrict__ s_lo, int tid) {
    #pragma unroll
    for (int it = 0; it < 5; ++it) {
        int i = tid + it * 256;
        if (i < 1056) {
            int gg = i & 3, cell = i >> 2;
            int off = cell * CI_PAD + gg * 8;
            *(uint4*)&s_hi[off] = vh[it];
            *(uint4*)&s_lo[off] = vl[it];
        }
    }
}

// ---------------------------------------------------------------------------
// Weights: all 9 taps of one ci-chunk (one co-half). 18 uint2 per thread.
// ---------------------------------------------------------------------------
__device__ __forceinline__ void wload9(const _Float16* __restrict__ wh,
                                       const _Float16* __restrict__ wl,
                                       int chunk, int ch, int tid,
                                       uint2* uh, uint2* ul) {
    #pragma unroll
    for (int tap = 0; tap < 9; ++tap) {
        size_t base = (size_t)((tap * 2 + chunk) * 2 + ch) * 1024 + tid * 4;
        uh[tap] = *(const uint2*)(wh + base);
        ul[tap] = *(const uint2*)(wl + base);
    }
}
__device__ __forceinline__ void wwrite9(const uint2* uh, const uint2* ul,
                                        _Float16 (*sw)[2][1024], int tid) {
    int co = tid >> 3, j = tid & 7;
    int pos = ((j >> 1) ^ (co ^ (co >> 2))) & 3;       // granule swizzle (verified r3)
    int off = co * 32 + pos * 8 + (j & 1) * 4;
    #pragma unroll
    for (int tap = 0; tap < 9; ++tap) {
        *(uint2*)&sw[tap][0][off] = uh[tap];
        *(uint2*)&sw[tap][1][off] = ul[tap];
    }
}

// ---------------------------------------------------------------------------
// One chunk's 9-tap MFMA run (108 MFMAs), barrier-free.
// ---------------------------------------------------------------------------
__device__ __forceinline__ void chunk_mfma(const _Float16* __restrict__ s_in_h,
    const _Float16* __restrict__ s_in_l, _Float16 (*s_w)[2][1024],
    int wv, int lg, int ln, int aoff, f32x4 acc1[2][2], f32x4 acc2[2][2]) {
    #pragma unroll
    for (int tap = 0; tap < 9; ++tap) {
        const int ty = tap / 3, tx = tap - ty * 3;
        half8 afh[2], afl[2];
        #pragma unroll
        for (int ct = 0; ct < 2; ++ct) {
            afh[ct] = *(const half8*)&s_w[tap][0][ct * 512 + aoff];
            afl[ct] = *(const half8*)&s_w[tap][1][ct * 512 + aoff];
        }
        half8 bfh[2], bfl[2];
        #pragma unroll
        for (int st = 0; st < 2; ++st) {
            int sp = wv * 32 + st * 16 + ln;
            int boff = (((sp >> 6) + ty) * 66 + (sp & 63) + tx) * CI_PAD + lg * 8;
            bfh[st] = *(const half8*)&s_in_h[boff];
            bfl[st] = *(const half8*)&s_in_l[boff];
        }
        #pragma unroll
        for (int ct = 0; ct < 2; ++ct)
            #pragma unroll
            for (int st = 0; st < 2; ++st) {
                acc1[ct][st] = __builtin_amdgcn_mfma_f32_16x16x32_f16(afh[ct], bfh[st], acc1[ct][st], 0, 0, 0);
                acc2[ct][st] = __builtin_amdgcn_mfma_f32_16x16x32_f16(afh[ct], bfl[st], acc2[ct][st], 0, 0, 0);
                acc2[ct][st] = __builtin_amdgcn_mfma_f32_16x16x32_f16(afl[ct], bfh[st], acc2[ct][st], 0, 0, 0);
            }
    }
}

// ---------------------------------------------------------------------------
// Conv core v4b: 3 barriers; chunk-resident weights; epilogue-operand prefetch
// issued AFTER B0 (hides under chunk-0 MFMAs, kept out of B0's drain).
// NO setprio (R11 A/B showed it regresses in this lockstep structure).
// ---------------------------------------------------------------------------
template<class PF>
__device__ __forceinline__ void conv_core(const _Float16* __restrict__ in_h,
    const _Float16* __restrict__ in_l, const _Float16* __restrict__ wh,
    const _Float16* __restrict__ wl, int n, int y0, int ch, int tid,
    f32x4 acc1[2][2], f32x4 acc2[2][2],
    _Float16* s_in_h, _Float16* s_in_l, _Float16 (*s_w)[2][1024], PF&& prefetch) {

    int wv = tid >> 6, l = tid & 63, lg = l >> 4, ln = l & 15;
    int aoff = ln * 32 + ((lg ^ ln ^ (ln >> 2)) & 3) * 8;

    // initial stage: input chunk0 + weights chunk0 (only these drain at B0)
    stage_pl(in_h, in_l, n, y0, 0, s_in_h, s_in_l, tid);
    {
        uint2 w0h[9], w0l[9];
        wload9(wh, wl, 0, ch, tid, w0h, w0l);
        wwrite9(w0h, w0l, s_w, tid);
    }
    __syncthreads();                                   // B0

    // chunk-1 staging loads, then epilogue-operand prefetch: all complete
    // under chunk-0's ~108-MFMA run, already done by B1's drain.
    uint4 sh1[5], sl1[5];
    uint2 w1h[9], w1l[9];
    stage_issue2(in_h, in_l, n, y0, 1, tid, sh1, sl1);
    wload9(wh, wl, 1, ch, tid, w1h, w1l);
    prefetch();

    chunk_mfma(s_in_h, s_in_l, s_w, wv, lg, ln, aoff, acc1, acc2);

    __syncthreads();                                   // B1: reads of c0 done
    stage_write2(sh1, sl1, s_in_h, s_in_l, tid);
    wwrite9(w1h, w1l, s_w, tid);
    __syncthreads();                                   // B2: c1 visible

    chunk_mfma(s_in_h, s_in_l, s_w, wv, lg, ln, aoff, acc1, acc2);
}

// ---------------------------------------------------------------------------
// Kernel A: f = sigmoid(conv(prev_y, w_rz) + b_rz + xi_i); a = prev_y * f.
// ---------------------------------------------------------------------------
template<bool ZERO>
__global__ __launch_bounds__(256, 2) void kA(
    const _Float16* __restrict__ y_hi, const _Float16* __restrict__ y_lo,
    const _Float16* __restrict__ wh, const _Float16* __restrict__ wl,
    const float* __restrict__ b_rz, const float* __restrict__ xt_t,
    float* __restrict__ f_out,
    _Float16* __restrict__ a_hi, _Float16* __restrict__ a_lo) {

    __shared__ __align__(16) _Float16 s_in_h[IN_LDS];
    __shared__ __align__(16) _Float16 s_in_l[IN_LDS];
    __shared__ __align__(16) _Float16 s_w[9][2][1024];

    int tid = threadIdx.x, wv = tid >> 6, l = tid & 63, lg = l >> 4, ln = l & 15;
    int bid = ((blockIdx.x & 7) << 6) | (blockIdx.x >> 3);   // XCD swizzle
    int n = bid >> 6, strip = (bid >> 1) & 31, ch = bid & 1, y0 = strip * 2;

    float xi_r[2][2][4];
    half4 pyh_r[2][2], pyl_r[2][2];
    float brz_[2][4];
    auto prefetch = [&]() {
        #pragma unroll
        for (int ct = 0; ct < 2; ++ct) {
            #pragma unroll
            for (int st = 0; st < 2; ++st) {
                int sp = wv * 32 + st * 16 + ln, row = y0 + (sp >> 6), col = sp & 63;
                size_t pb = (((size_t)n * 64 + row) * 64 + col) * 64
                          + ch * 32 + ct * 16 + lg * 4;
                if (!ZERO) {
                    pyh_r[ct][st] = *(const half4*)(y_hi + pb);
                    pyl_r[ct][st] = *(const half4*)(y_lo + pb);
                } else {
                    pyh_r[ct][st] = half4{}; pyl_r[ct][st] = half4{};
                }
                #pragma unroll
                for (int r = 0; r < 4; ++r) {
                    int co = ch * 32 + ct * 16 + lg * 4 + r;
                    xi_r[ct][st][r] = xt_t[((n * 2 * CCH + co) * HH + row) * WW + col];
                }
            }
            #pragma unroll
            for (int r = 0; r < 4; ++r)
                brz_[ct][r] = b_rz[ch * 32 + ct * 16 + lg * 4 + r];
        }
    };

    f32x4 acc1[2][2] = {}, acc2[2][2] = {};
    if (!ZERO)
        conv_core(y_hi, y_lo, wh, wl, n, y0, ch, tid, acc1, acc2,
                  s_in_h, s_in_l, s_w, prefetch);
    else
        prefetch();

    #pragma unroll
    for (int ct = 0; ct < 2; ++ct)
        #pragma unroll
        for (int st = 0; st < 2; ++st) {
            int sp = wv * 32 + st * 16 + ln, row = y0 + (sp >> 6), col = sp & 63;
            size_t pb = (((size_t)n * 64 + row) * 64 + col) * 64 + ch * 32 + ct * 16 + lg * 4;
            half4 avh, avl;
            #pragma unroll
            for (int r = 0; r < 4; ++r) {
                int co = ch * 32 + ct * 16 + lg * 4 + r;
                float conv = ZERO ? 0.0f
                    : (acc1[ct][st][r] + acc2[ct][st][r] * (1.0f / 2048.0f));
                int idx = ((n * CCH + co) * HH + row) * WW + col;
                float s = conv + brz_[ct][r] + xi_r[ct][st][r];
                float f = 1.0f / (1.0f + expf(-s));
                f_out[idx] = f;
                float py = (float)pyh_r[ct][st][r] + (float)pyl_r[ct][st][r] * (1.0f / 2048.0f);
                float a = py * f;
                _Float16 hi, lo; split2h(a, hi, lo);
                avh[r] = hi; avl[r] = lo;
            }
            if (!ZERO) {
                *(half4*)(a_hi + pb) = avh;
                *(half4*)(a_lo + pb) = avl;
            }
        }
}

// ---------------------------------------------------------------------------
// Kernel B: g = tanh(conv(a, w_f) + b_f + xi_f); GRU/spike update; outputs +
// split y planes.
// ---------------------------------------------------------------------------
template<bool ZERO>
__global__ __launch_bounds__(256, 2) void kB(
    const _Float16* __restrict__ a_hi, const _Float16* __restrict__ a_lo,
    const _Float16* __restrict__ wh, const _Float16* __restrict__ wl,
    const float* __restrict__ b_f, const float* __restrict__ xt_t,
    const float* __restrict__ f_in, const float* __restrict__ thr_rp,
    float* __restrict__ h_buf, float* __restrict__ ys,
    float* __restrict__ ev, float* __restrict__ nd,
    _Float16* __restrict__ y_hi, _Float16* __restrict__ y_lo) {

    __shared__ __align__(16) _Float16 s_in_h[IN_LDS];
    __shared__ __align__(16) _Float16 s_in_l[IN_LDS];
    __shared__ __align__(16) _Float16 s_w[9][2][1024];

    int tid = threadIdx.x, wv = tid >> 6, l = tid & 63, lg = l >> 4, ln = l & 15;
    int bid = ((blockIdx.x & 7) << 6) | (blockIdx.x >> 3);
    int n = bid >> 6, strip = (bid >> 1) & 31, ch = bid & 1, y0 = strip * 2;

    float xi_r[2][2][4], f_r[2][2][4], h_r[2][2][4];
    float thr_r[2], bf_[2][4];
    auto prefetch = [&]() {
        #pragma unroll
        for (int st = 0; st < 2; ++st) {
            int sp = wv * 32 + st * 16 + ln, row = y0 + (sp >> 6), col = sp & 63;
            thr_r[st] = thr_rp[row * WW + col];
        }
        #pragma unroll
        for (int ct = 0; ct < 2; ++ct) {
            #pragma unroll
            for (int st = 0; st < 2; ++st) {
                int sp = wv * 32 + st * 16 + ln, row = y0 + (sp >> 6), col = sp & 63;
                #pragma unroll
                for (int r = 0; r < 4; ++r) {
                    int co = ch * 32 + ct * 16 + lg * 4 + r;
                    int idx = ((n * CCH + co) * HH + row) * WW + col;
                    xi_r[ct][st][r] = xt_t[((n * 2 * CCH + CCH + co) * HH + row) * WW + col];
                    f_r[ct][st][r]  = f_in[idx];
                    h_r[ct][st][r]  = ZERO ? 0.0f : h_buf[idx];
                }
            }
            #pragma unroll
            for (int r = 0; r < 4; ++r)
                bf_[ct][r] = b_f[ch * 32 + ct * 16 + lg * 4 + r];
        }
    };

    f32x4 acc1[2][2] = {}, acc2[2][2] = {};
    if (!ZERO)
        conv_core(a_hi, a_lo, wh, wl, n, y0, ch, tid, acc1, acc2,
                  s_in_h, s_in_l, s_w, prefetch);
    else
        prefetch();

    #pragma unroll
    for (int ct = 0; ct < 2; ++ct)
        #pragma unroll
        for (int st = 0; st < 2; ++st) {
            int sp = wv * 32 + st * 16 + ln, row = y0 + (sp >> 6), col = sp & 63;
            float thr = 1.0f / (1.0f + expf(-thr_r[st]));
            size_t pb = (((size_t)n * 64 + row) * 64 + col) * 64 + ch * 32 + ct * 16 + lg * 4;
            half4 yvh, yvl;
            #pragma unroll
            for (int r = 0; r < 4; ++r) {
                int co = ch * 32 + ct * 16 + lg * 4 + r;
                float conv = ZERO ? 0.0f
                    : (acc1[ct][st][r] + acc2[ct][st][r] * (1.0f / 2048.0f));
                int idx = ((n * CCH + co) * HH + row) * WW + col;
                float s  = conv + bf_[ct][r] + xi_r[ct][st][r];
                float e2 = expf(2.0f * s);
                float g  = 1.0f - 2.0f / (e2 + 1.0f);       // tanh(s)
                float f  = f_r[ct][st][r];
                float hp = h_r[ct][st][r];
                float h  = (1.0f - f) * hp + f * g;
                float d  = h - thr;
                bool  e  = d > 0.0f;
                float y  = e ? h : 0.0f;
                ys[idx] = y;
                ev[idx] = e ? 1.0f : 0.0f;
                nd[idx] = (d < 0.0f) ? (thr - h) : 0.0f;
                h_buf[idx] = e ? d : h;                     // h - event*thr
                _Float16 hi, lo; split2h(y, hi, lo);
                yvh[r] = hi; yvl[r] = lo;
            }
            *(half4*)(y_hi + pb) = yvh;
            *(half4*)(y_lo + pb) = yvl;
        }
}

// ---------------------------------------------------------------------------
extern "C" void kernel_launch(void* const* d_in, const int* in_sizes, int n_in,
                              void* d_out, int out_size, void* d_ws, size_t ws_size,
                              hipStream_t stream) {
    (void)in_sizes; (void)n_in; (void)out_size; (void)ws_size;

    const float* xt     = (const float*)d_in[0];
    const float* w_rz   = (const float*)d_in[1];
    const float* b_rz   = (const float*)d_in[2];
    const float* w_f    = (const float*)d_in[3];
    const float* b_f    = (const float*)d_in[4];
    const float* thr_rp = (const float*)d_in[5];

    float* out = (float*)d_out;
    _Float16* y_hi = (_Float16*)d_ws;                 // 4 MB each plane
    _Float16* y_lo = y_hi + NCHW;
    _Float16* a_hi = y_lo + NCHW;
    _Float16* a_lo = a_hi + NCHW;
    float*    f_buf = (float*)(a_lo + NCHW);          // 8 MB
    float*    h_buf = f_buf + NCHW;                   // 8 MB
    _Float16* w_hi  = (_Float16*)(h_buf + NCHW);      // 73728 halves
    _Float16* w_lo  = w_hi + 73728;                   // total ~32.3 MB

    float* ys0 = out;
    float* ev0 = out + (size_t)T_STEPS * NCHW;
    float* nd0 = ev0 + (size_t)T_STEPS * NCHW;

    prep_w<<<288, 256, 0, stream>>>(w_rz, w_f, w_hi, w_lo);
    const _Float16* whA = w_hi,         * wlA = w_lo;
    const _Float16* whB = w_hi + 36864, * wlB = w_lo + 36864;

    dim3 grid(512), block(256);
    for (int t = 0; t < T_STEPS; ++t) {
        const float* xt_t = xt + (size_t)t * XTSTR;
        float* ys_t = ys0 + (size_t)t * NCHW;
        float* ev_t = ev0 + (size_t)t * NCHW;
        float* nd_t = nd0 + (size_t)t * NCHW;
        if (t == 0) {
            kA<true><<<grid, block, 0, stream>>>(y_hi, y_lo, whA, wlA, b_rz, xt_t,
                                                 f_buf, a_hi, a_lo);
            kB<true><<<grid, block, 0, stream>>>(a_hi, a_lo, whB, wlB, b_f, xt_t,
                                                 f_buf, thr_rp, h_buf,
                                                 ys_t, ev_t, nd_t, y_hi, y_lo);
        } else {
            kA<false><<<grid, block, 0, stream>>>(y_hi, y_lo, whA, wlA, b_rz, xt_t,
                                                  f_buf, a_hi, a_lo);
            kB<false><<<grid, block, 0, stream>>>(a_hi, a_lo, whB, wlB, b_f, xt_t,
                                                  f_buf, thr_rp, h_buf,
                                                  ys_t, ev_t, nd_t, y_hi, y_lo);
        }
    }
}

// Round 13
// 571.998 us; speedup vs baseline: 1.1038x; 1.0199x over previous
//
#include <hip/hip_runtime.h>
#include <cstdint>

typedef _Float16 half8 __attribute__((ext_vector_type(8)));
typedef _Float16 half4 __attribute__((ext_vector_type(4)));
typedef float f32x4 __attribute__((ext_vector_type(4)));

#define T_STEPS 16
#define NB 8
#define CCH 64
#define HH 64
#define WW 64
#define HW 4096
#define NCHW (NB * CCH * HW)          // 2097152
#define XTSTR (NB * 2 * CCH * HW)

#define CI_PAD 40                      // halves per (r,c) cell: 80B stride, 16B aligned
#define IN_LDS (4 * 66 * CI_PAD)       // 21120 B per plane

__device__ __forceinline__ unsigned short h_bits(_Float16 h) {
    union { _Float16 h; unsigned short u; } v; v.h = h; return v.u;
}
__device__ __forceinline__ float h2f(uint32_t b) {
    union { unsigned short u; _Float16 h; } v; v.u = (unsigned short)b; return (float)v.h;
}
__device__ __forceinline__ void split2h(float x, _Float16& hi, _Float16& lo) {
    hi = (_Float16)x;
    lo = (_Float16)((x - (float)hi) * 2048.0f);
}
__device__ __forceinline__ uint32_t packf(float x) {
    _Float16 hi, lo; split2h(x, hi, lo);
    return ((uint32_t)h_bits(hi) << 16) | h_bits(lo);
}
__device__ __forceinline__ float unpackf(uint32_t u) {
    return h2f(u >> 16) + h2f(u & 0xFFFFu) * (1.0f / 2048.0f);
}

// ---------------------------------------------------------------------------
// Input staging (chunk of 32 ci, both planes). Direct form and T14 split form.
// ---------------------------------------------------------------------------
__device__ __forceinline__ void stage_pl(const _Float16* __restrict__ ph,
                                         const _Float16* __restrict__ pl,
                                         int n, int y0, int chunk,
                                         _Float16* __restrict__ s_hi,
                                         _Float16* __restrict__ s_lo, int tid) {
    #pragma unroll
    for (int it = 0; it < 5; ++it) {
        int i = tid + it * 256;
        if (i >= 1056) break;                 // 4 rows x 66 cols x 4 granules
        int gg = i & 3; int tmp = i >> 2; int c = tmp % 66; int r = tmp / 66;
        int gr = y0 - 1 + r, gc = c - 1;
        uint4 uh = make_uint4(0, 0, 0, 0), ul = make_uint4(0, 0, 0, 0);
        if ((unsigned)gr < 64u && (unsigned)gc < 64u) {
            size_t base = (((size_t)n * 64 + gr) * 64 + gc) * 64 + chunk * 32 + gg * 8;
            uh = *(const uint4*)(ph + base);
            ul = *(const uint4*)(pl + base);
        }
        int off = (r * 66 + c) * CI_PAD + gg * 8;
        *(uint4*)&s_hi[off] = uh;
        *(uint4*)&s_lo[off] = ul;
    }
}

__device__ __forceinline__ void stage_issue2(const _Float16* __restrict__ ph,
                                             const _Float16* __restrict__ pl,
                                             int n, int y0, int chunk, int tid,
                                             uint4* vh, uint4* vl) {
    #pragma unroll
    for (int it = 0; it < 5; ++it) {
        int i = tid + it * 256;
        vh[it] = make_uint4(0, 0, 0, 0);
        vl[it] = make_uint4(0, 0, 0, 0);
        if (i < 1056) {
            int gg = i & 3; int tmp = i >> 2; int c = tmp % 66; int r = tmp / 66;
            int gr = y0 - 1 + r, gc = c - 1;
            if ((unsigned)gr < 64u && (unsigned)gc < 64u) {
                size_t base = (((size_t)n * 64 + gr) * 64 + gc) * 64 + chunk * 32 + gg * 8;
                vh[it] = *(const uint4*)(ph + base);
                vl[it] = *(const uint4*)(pl + base);
            }
        }
    }
}
__device__ __forceinline__ void stage_write2(const uint4* vh, const uint4* vl,
                                             _Float16* __restrict__ s_hi,
                                             _Float16* __restrict__ s_lo, int tid) {
    #pragma unroll
    for (int it = 0; it < 5; ++it) {
        int i = tid + it * 256;
        if (i < 1056) {
            int gg = i & 3, cell = i >> 2;
            int off = cell * CI_PAD + gg * 8;
            *(uint4*)&s_hi[off] = vh[it];
            *(uint4*)&s_lo[off] = vl[it];
        }
    }
}

// ---------------------------------------------------------------------------
// Weights: all 9 taps of one ci-chunk (one co-half). 18 uint2 per thread.
// ---------------------------------------------------------------------------
__device__ __forceinline__ void wload9(const _Float16* __restrict__ wh,
                                       const _Float16* __restrict__ wl,
                                       int chunk, int ch, int tid,
                                       uint2* uh, uint2* ul) {
    #pragma unroll
    for (int tap = 0; tap < 9; ++tap) {
        size_t base = (size_t)((tap * 2 + chunk) * 2 + ch) * 1024 + tid * 4;
        uh[tap] = *(const uint2*)(wh + base);
        ul[tap] = *(const uint2*)(wl + base);
    }
}
__device__ __forceinline__ void wwrite9(const uint2* uh, const uint2* ul,
                                        _Float16 (*sw)[2][1024], int tid) {
    int co = tid >> 3, j = tid & 7;
    int pos = ((j >> 1) ^ (co ^ (co >> 2))) & 3;       // granule swizzle (verified r3)
    int off = co * 32 + pos * 8 + (j & 1) * 4;
    #pragma unroll
    for (int tap = 0; tap < 9; ++tap) {
        *(uint2*)&sw[tap][0][off] = uh[tap];
        *(uint2*)&sw[tap][1][off] = ul[tap];
    }
}

// ---------------------------------------------------------------------------
// One chunk's 9-tap MFMA run (108 MFMAs), barrier-free.
// ---------------------------------------------------------------------------
__device__ __forceinline__ void chunk_mfma(const _Float16* __restrict__ s_in_h,
    const _Float16* __restrict__ s_in_l, _Float16 (*s_w)[2][1024],
    int wv, int lg, int ln, int aoff, f32x4 acc1[2][2], f32x4 acc2[2][2]) {
    #pragma unroll
    for (int tap = 0; tap < 9; ++tap) {
        const int ty = tap / 3, tx = tap - ty * 3;
        half8 afh[2], afl[2];
        #pragma unroll
        for (int ct = 0; ct < 2; ++ct) {
            afh[ct] = *(const half8*)&s_w[tap][0][ct * 512 + aoff];
            afl[ct] = *(const half8*)&s_w[tap][1][ct * 512 + aoff];
        }
        half8 bfh[2], bfl[2];
        #pragma unroll
        for (int st = 0; st < 2; ++st) {
            int sp = wv * 32 + st * 16 + ln;
            int boff = (((sp >> 6) + ty) * 66 + (sp & 63) + tx) * CI_PAD + lg * 8;
            bfh[st] = *(const half8*)&s_in_h[boff];
            bfl[st] = *(const half8*)&s_in_l[boff];
        }
        #pragma unroll
        for (int ct = 0; ct < 2; ++ct)
            #pragma unroll
            for (int st = 0; st < 2; ++st) {
                acc1[ct][st] = __builtin_amdgcn_mfma_f32_16x16x32_f16(afh[ct], bfh[st], acc1[ct][st], 0, 0, 0);
                acc2[ct][st] = __builtin_amdgcn_mfma_f32_16x16x32_f16(afh[ct], bfl[st], acc2[ct][st], 0, 0, 0);
                acc2[ct][st] = __builtin_amdgcn_mfma_f32_16x16x32_f16(afl[ct], bfh[st], acc2[ct][st], 0, 0, 0);
            }
    }
}

// ---------------------------------------------------------------------------
// Conv core v4b: 3 barriers; chunk-resident weights; epilogue-operand prefetch
// issued AFTER B0 (hides under chunk-0 MFMAs, kept out of B0's drain).
// No setprio (R11/R12 A/B: regresses in this lockstep structure).
// ---------------------------------------------------------------------------
template<class PF>
__device__ __forceinline__ void conv_core(const _Float16* __restrict__ in_h,
    const _Float16* __restrict__ in_l, const _Float16* __restrict__ wh,
    const _Float16* __restrict__ wl, int n, int y0, int ch, int tid,
    f32x4 acc1[2][2], f32x4 acc2[2][2],
    _Float16* s_in_h, _Float16* s_in_l, _Float16 (*s_w)[2][1024], PF&& prefetch) {

    int wv = tid >> 6, l = tid & 63, lg = l >> 4, ln = l & 15;
    int aoff = ln * 32 + ((lg ^ ln ^ (ln >> 2)) & 3) * 8;

    // initial stage: input chunk0 + weights chunk0 (only these drain at B0)
    stage_pl(in_h, in_l, n, y0, 0, s_in_h, s_in_l, tid);
    {
        uint2 w0h[9], w0l[9];
        wload9(wh, wl, 0, ch, tid, w0h, w0l);
        wwrite9(w0h, w0l, s_w, tid);
    }
    __syncthreads();                                   // B0

    // chunk-1 staging loads, then epilogue-operand prefetch: all complete
    // under chunk-0's ~108-MFMA run, already done by B1's drain.
    uint4 sh1[5], sl1[5];
    uint2 w1h[9], w1l[9];
    stage_issue2(in_h, in_l, n, y0, 1, tid, sh1, sl1);
    wload9(wh, wl, 1, ch, tid, w1h, w1l);
    prefetch();

    chunk_mfma(s_in_h, s_in_l, s_w, wv, lg, ln, aoff, acc1, acc2);

    __syncthreads();                                   // B1: reads of c0 done
    stage_write2(sh1, sl1, s_in_h, s_in_l, tid);
    wwrite9(w1h, w1l, s_w, tid);
    __syncthreads();                                   // B2: c1 visible

    chunk_mfma(s_in_h, s_in_l, s_w, wv, lg, ln, aoff, acc1, acc2);
}

// ---------------------------------------------------------------------------
// Kernel A: f = sigmoid(conv(prev_y, w_rz) + b_rz + xi_i); a = prev_y * f.
// f transported as packed hi|lo u32. At t=0 (ZERO), this kernel also performs
// the one-time weight prepack (weights first consumed at t=1).
// ---------------------------------------------------------------------------
template<bool ZERO>
__global__ __launch_bounds__(256, 2) void kA(
    const _Float16* __restrict__ y_hi, const _Float16* __restrict__ y_lo,
    const _Float16* __restrict__ wh, const _Float16* __restrict__ wl,
    const float* __restrict__ b_rz, const float* __restrict__ xt_t,
    uint32_t* __restrict__ f_out,
    _Float16* __restrict__ a_hi, _Float16* __restrict__ a_lo,
    const float* __restrict__ w_rz_raw, const float* __restrict__ w_f_raw,
    _Float16* __restrict__ wpk_hi, _Float16* __restrict__ wpk_lo) {

    __shared__ __align__(16) _Float16 s_in_h[IN_LDS];
    __shared__ __align__(16) _Float16 s_in_l[IN_LDS];
    __shared__ __align__(16) _Float16 s_w[9][2][1024];

    int tid = threadIdx.x, wv = tid >> 6, l = tid & 63, lg = l >> 4, ln = l & 15;
    int bid = ((blockIdx.x & 7) << 6) | (blockIdx.x >> 3);   // XCD swizzle
    int n = bid >> 6, strip = (bid >> 1) & 31, ch = bid & 1, y0 = strip * 2;

    if (ZERO) {
        // one-time weight prepack (512x256 threads cover 73728 elements)
        int i = blockIdx.x * 256 + tid;
        if (i < 2 * 9 * 2 * 2 * 32 * 32) {
            int ci = i & 31, co = (i >> 5) & 31, chh = (i >> 10) & 1, chunk = (i >> 11) & 1;
            int gt = i >> 12; int tap = gt % 9; int g = gt / 9;
            const float* w = g ? w_f_raw : w_rz_raw;
            float v = w[(size_t)((chh * 32 + co) * CCH + (chunk * 32 + ci)) * 9 + tap];
            _Float16 hi, lo; split2h(v, hi, lo);
            wpk_hi[i] = hi; wpk_lo[i] = lo;
        }
    }

    float xi_r[2][2][4];
    half4 pyh_r[2][2], pyl_r[2][2];
    float brz_[2][4];
    auto prefetch = [&]() {
        #pragma unroll
        for (int ct = 0; ct < 2; ++ct) {
            #pragma unroll
            for (int st = 0; st < 2; ++st) {
                int sp = wv * 32 + st * 16 + ln, row = y0 + (sp >> 6), col = sp & 63;
                size_t pb = (((size_t)n * 64 + row) * 64 + col) * 64
                          + ch * 32 + ct * 16 + lg * 4;
                if (!ZERO) {
                    pyh_r[ct][st] = *(const half4*)(y_hi + pb);
                    pyl_r[ct][st] = *(const half4*)(y_lo + pb);
                } else {
                    pyh_r[ct][st] = half4{}; pyl_r[ct][st] = half4{};
                }
                #pragma unroll
                for (int r = 0; r < 4; ++r) {
                    int co = ch * 32 + ct * 16 + lg * 4 + r;
                    xi_r[ct][st][r] = xt_t[((n * 2 * CCH + co) * HH + row) * WW + col];
                }
            }
            #pragma unroll
            for (int r = 0; r < 4; ++r)
                brz_[ct][r] = b_rz[ch * 32 + ct * 16 + lg * 4 + r];
        }
    };

    f32x4 acc1[2][2] = {}, acc2[2][2] = {};
    if (!ZERO)
        conv_core(y_hi, y_lo, wh, wl, n, y0, ch, tid, acc1, acc2,
                  s_in_h, s_in_l, s_w, prefetch);
    else
        prefetch();

    #pragma unroll
    for (int ct = 0; ct < 2; ++ct)
        #pragma unroll
        for (int st = 0; st < 2; ++st) {
            int sp = wv * 32 + st * 16 + ln, row = y0 + (sp >> 6), col = sp & 63;
            size_t pb = (((size_t)n * 64 + row) * 64 + col) * 64 + ch * 32 + ct * 16 + lg * 4;
            half4 avh, avl;
            #pragma unroll
            for (int r = 0; r < 4; ++r) {
                int co = ch * 32 + ct * 16 + lg * 4 + r;
                float conv = ZERO ? 0.0f
                    : (acc1[ct][st][r] + acc2[ct][st][r] * (1.0f / 2048.0f));
                int idx = ((n * CCH + co) * HH + row) * WW + col;
                float s = conv + brz_[ct][r] + xi_r[ct][st][r];
                float f = 1.0f / (1.0f + expf(-s));
                f_out[idx] = packf(f);
                float py = (float)pyh_r[ct][st][r] + (float)pyl_r[ct][st][r] * (1.0f / 2048.0f);
                float a = py * f;
                _Float16 hi, lo; split2h(a, hi, lo);
                avh[r] = hi; avl[r] = lo;
            }
            if (!ZERO) {
                *(half4*)(a_hi + pb) = avh;
                *(half4*)(a_lo + pb) = avl;
            }
        }
}

// ---------------------------------------------------------------------------
// Kernel B: g = tanh(conv(a, w_f) + b_f + xi_f); GRU/spike update; outputs +
// split y planes. f read as packed u32.
// ---------------------------------------------------------------------------
template<bool ZERO>
__global__ __launch_bounds__(256, 2) void kB(
    const _Float16* __restrict__ a_hi, const _Float16* __restrict__ a_lo,
    const _Float16* __restrict__ wh, const _Float16* __restrict__ wl,
    const float* __restrict__ b_f, const float* __restrict__ xt_t,
    const uint32_t* __restrict__ f_in, const float* __restrict__ thr_rp,
    float* __restrict__ h_buf, float* __restrict__ ys,
    float* __restrict__ ev, float* __restrict__ nd,
    _Float16* __restrict__ y_hi, _Float16* __restrict__ y_lo) {

    __shared__ __align__(16) _Float16 s_in_h[IN_LDS];
    __shared__ __align__(16) _Float16 s_in_l[IN_LDS];
    __shared__ __align__(16) _Float16 s_w[9][2][1024];

    int tid = threadIdx.x, wv = tid >> 6, l = tid & 63, lg = l >> 4, ln = l & 15;
    int bid = ((blockIdx.x & 7) << 6) | (blockIdx.x >> 3);
    int n = bid >> 6, strip = (bid >> 1) & 31, ch = bid & 1, y0 = strip * 2;

    float xi_r[2][2][4], f_r[2][2][4], h_r[2][2][4];
    float thr_r[2], bf_[2][4];
    auto prefetch = [&]() {
        #pragma unroll
        for (int st = 0; st < 2; ++st) {
            int sp = wv * 32 + st * 16 + ln, row = y0 + (sp >> 6), col = sp & 63;
            thr_r[st] = thr_rp[row * WW + col];
        }
        #pragma unroll
        for (int ct = 0; ct < 2; ++ct) {
            #pragma unroll
            for (int st = 0; st < 2; ++st) {
                int sp = wv * 32 + st * 16 + ln, row = y0 + (sp >> 6), col = sp & 63;
                #pragma unroll
                for (int r = 0; r < 4; ++r) {
                    int co = ch * 32 + ct * 16 + lg * 4 + r;
                    int idx = ((n * CCH + co) * HH + row) * WW + col;
                    xi_r[ct][st][r] = xt_t[((n * 2 * CCH + CCH + co) * HH + row) * WW + col];
                    f_r[ct][st][r]  = unpackf(f_in[idx]);
                    h_r[ct][st][r]  = ZERO ? 0.0f : h_buf[idx];
                }
            }
            #pragma unroll
            for (int r = 0; r < 4; ++r)
                bf_[ct][r] = b_f[ch * 32 + ct * 16 + lg * 4 + r];
        }
    };

    f32x4 acc1[2][2] = {}, acc2[2][2] = {};
    if (!ZERO)
        conv_core(a_hi, a_lo, wh, wl, n, y0, ch, tid, acc1, acc2,
                  s_in_h, s_in_l, s_w, prefetch);
    else
        prefetch();

    #pragma unroll
    for (int ct = 0; ct < 2; ++ct)
        #pragma unroll
        for (int st = 0; st < 2; ++st) {
            int sp = wv * 32 + st * 16 + ln, row = y0 + (sp >> 6), col = sp & 63;
            float thr = 1.0f / (1.0f + expf(-thr_r[st]));
            size_t pb = (((size_t)n * 64 + row) * 64 + col) * 64 + ch * 32 + ct * 16 + lg * 4;
            half4 yvh, yvl;
            #pragma unroll
            for (int r = 0; r < 4; ++r) {
                int co = ch * 32 + ct * 16 + lg * 4 + r;
                float conv = ZERO ? 0.0f
                    : (acc1[ct][st][r] + acc2[ct][st][r] * (1.0f / 2048.0f));
                int idx = ((n * CCH + co) * HH + row) * WW + col;
                float s  = conv + bf_[ct][r] + xi_r[ct][st][r];
                float e2 = expf(2.0f * s);
                float g  = 1.0f - 2.0f / (e2 + 1.0f);       // tanh(s)
                float f  = f_r[ct][st][r];
                float hp = h_r[ct][st][r];
                float h  = (1.0f - f) * hp + f * g;
                float d  = h - thr;
                bool  e  = d > 0.0f;
                float y  = e ? h : 0.0f;
                ys[idx] = y;
                ev[idx] = e ? 1.0f : 0.0f;
                nd[idx] = (d < 0.0f) ? (thr - h) : 0.0f;
                h_buf[idx] = e ? d : h;                     // h - event*thr
                _Float16 hi, lo; split2h(y, hi, lo);
                yvh[r] = hi; yvl[r] = lo;
            }
            *(half4*)(y_hi + pb) = yvh;
            *(half4*)(y_lo + pb) = yvl;
        }
}

// ---------------------------------------------------------------------------
extern "C" void kernel_launch(void* const* d_in, const int* in_sizes, int n_in,
                              void* d_out, int out_size, void* d_ws, size_t ws_size,
                              hipStream_t stream) {
    (void)in_sizes; (void)n_in; (void)out_size; (void)ws_size;

    const float* xt     = (const float*)d_in[0];
    const float* w_rz   = (const float*)d_in[1];
    const float* b_rz   = (const float*)d_in[2];
    const float* w_f    = (const float*)d_in[3];
    const float* b_f    = (const float*)d_in[4];
    const float* thr_rp = (const float*)d_in[5];

    float* out = (float*)d_out;
    _Float16* y_hi = (_Float16*)d_ws;                 // 4 MB each plane
    _Float16* y_lo = y_hi + NCHW;
    _Float16* a_hi = y_lo + NCHW;
    _Float16* a_lo = a_hi + NCHW;
    uint32_t* f_buf = (uint32_t*)(a_lo + NCHW);       // 8 MB (packed hi|lo)
    float*    h_buf = (float*)(f_buf + NCHW);         // 8 MB
    _Float16* w_hi  = (_Float16*)(h_buf + NCHW);      // 73728 halves
    _Float16* w_lo  = w_hi + 73728;                   // total ~32.3 MB

    float* ys0 = out;
    float* ev0 = out + (size_t)T_STEPS * NCHW;
    float* nd0 = ev0 + (size_t)T_STEPS * NCHW;

    const _Float16* whA = w_hi,         * wlA = w_lo;
    const _Float16* whB = w_hi + 36864, * wlB = w_lo + 36864;

    dim3 grid(512), block(256);
    for (int t = 0; t < T_STEPS; ++t) {
        const float* xt_t = xt + (size_t)t * XTSTR;
        float* ys_t = ys0 + (size_t)t * NCHW;
        float* ev_t = ev0 + (size_t)t * NCHW;
        float* nd_t = nd0 + (size_t)t * NCHW;
        if (t == 0) {
            // kA<true> also performs the one-time weight prepack
            kA<true><<<grid, block, 0, stream>>>(y_hi, y_lo, whA, wlA, b_rz, xt_t,
                                                 f_buf, a_hi, a_lo,
                                                 w_rz, w_f, w_hi, w_lo);
            kB<true><<<grid, block, 0, stream>>>(a_hi, a_lo, whB, wlB, b_f, xt_t,
                                                 f_buf, thr_rp, h_buf,
                                                 ys_t, ev_t, nd_t, y_hi, y_lo);
        } else {
            kA<false><<<grid, block, 0, stream>>>(y_hi, y_lo, whA, wlA, b_rz, xt_t,
                                                  f_buf, a_hi, a_lo,
                                                  w_rz, w_f, w_hi, w_lo);
            kB<false><<<grid, block, 0, stream>>>(a_hi, a_lo, whB, wlB, b_f, xt_t,
                                                  f_buf, thr_rp, h_buf,
                                                  ys_t, ev_t, nd_t, y_hi, y_lo);
        }
    }
}